// Round 13
// baseline (207.974 us; speedup 1.0000x reference)
//
#include <hip/hip_runtime.h>
#include <math.h>

#define BB 8
#define QQ 100
#define CC 41
#define TT 50
#define PP 12544        // = 49 * 256
#define QP 112          // padded Q rows (7 * 16)
#define TP 64           // padded T rows (4 * 16)
#define KS 8            // split-K over P
#define KCH (PP / KS)   // 1568
#define NT (BB * TT)    // 400
#define NMASK (NT + BB * QQ)   // 1200
#define SPLIT 2         // sampler blocks per mask
#define NBH (PP / SPLIT)       // 6272 points per half

typedef _Float16 f16x8 __attribute__((ext_vector_type(8)));
typedef float f32x4 __attribute__((ext_vector_type(4)));

// ---------------------------------------------------------------------------
// sort_kernel: one block per batch. LDS-atomic counting sort of points into
// 16 16-row bins (y-locality). Slot order within a bin is nondeterministic;
// all consumers are permutation-invariant (fp jitter ~1e-6 << threshold).
// Entry: t.x/t.y = GLOBAL element indices of (r0,xb)/(r1,xb);
//        t.z=(wa,wb) f16x2 x-weights; t.w=(ya,yb) f16x2 y-weights (borders).
// ---------------------------------------------------------------------------
__global__ __launch_bounds__(1024) void sort_kernel(
    const float* __restrict__ coords, uint4* __restrict__ stb)
{
    int b = blockIdx.x;
    int tid = threadIdx.x;
    const float2* cd = (const float2*)coords + (size_t)b * PP;
    __shared__ int hist[16];
    __shared__ int cur[16];
    if (tid < 16) hist[tid] = 0;
    __syncthreads();
    for (int p = tid; p < PP; p += 1024) {
        float y = fmaf(cd[p].y, 256.f, -0.5f);
        int bin = min(max((int)floorf(y), 0), 255) >> 4;
        atomicAdd(&hist[bin], 1);
    }
    __syncthreads();
    if (tid == 0) {
        int acc = 0;
        for (int i = 0; i < 16; ++i) { cur[i] = acc; acc += hist[i]; }
    }
    __syncthreads();
    uint4* out = stb + (size_t)b * PP;
    for (int p = tid; p < PP; p += 1024) {
        float2 cc = cd[p];
        float x = fmaf(cc.x, 256.f, -0.5f);
        float y = fmaf(cc.y, 256.f, -0.5f);
        float x0f = floorf(x), y0f = floorf(y);
        int x0 = (int)x0f, y0 = (int)y0f;
        int bin = min(max(y0, 0), 255) >> 4;
        float wx = x - x0f, wy = y - y0f;
        int xb = min(max(x0, 0), 254);
        int r0 = min(max(y0, 0), 255);
        int r1 = min(y0 + 1, 255);
        float wa, wb;
        if (x0 < 0)        { wa = wx;       wb = 0.f; }
        else if (x0 > 254) { wa = 0.f;      wb = 1.f - wx; }
        else               { wa = 1.f - wx; wb = wx; }
        float ya = (y0 >= 0)  ? 1.f - wy : 0.f;
        float yb = (y0 < 255) ? wy       : 0.f;
        union { unsigned int u; _Float16 h[2]; } pw, pyw;
        pw.h[0] = (_Float16)wa;  pw.h[1] = (_Float16)wb;
        pyw.h[0] = (_Float16)ya; pyw.h[1] = (_Float16)yb;
        uint4 t;
        t.x = (unsigned int)(r0 * 256 + xb);
        t.y = (unsigned int)(r1 * 256 + xb);
        t.z = pw.u; t.w = pyw.u;
        int slot = atomicAdd(&cur[bin], 1);
        out[slot] = t;
    }
}

// ---------------------------------------------------------------------------
// sample_kernel: block (mask, half) of 256 thr, __launch_bounds__(256,4) so
// the compiler keeps 8-point batches (8 table uint4 + 32 gathers) live in
// VGPRs. Direct-global gathers; sorted order keeps the live window L2-hot.
// No LDS, no barriers until the final reduction. Per-half partial sums.
// ---------------------------------------------------------------------------
__global__ __launch_bounds__(256, 4) void sample_kernel(
    const float* __restrict__ tgt_masks, const float* __restrict__ pred_masks,
    const uint4* __restrict__ stb,
    _Float16* __restrict__ tm, _Float16* __restrict__ om, _Float16* __restrict__ sg,
    float* __restrict__ psum)
{
    __shared__ float red[4], red2[4];
    int bid = blockIdx.x;
    int id = bid >> 1;
    int half = bid & 1;
    int tid = threadIdx.x;
    bool is_t = id < NT;
    int b;
    const float* m;
    _Float16* dst;
    _Float16* dsg = nullptr;
    if (is_t) {
        b = id / TT;
        m = tgt_masks + (size_t)id * 65536;
        dst = tm + ((size_t)b * TP + (id % TT)) * PP;
    } else {
        int bq = id - NT;
        b = bq / QQ;
        m = pred_masks + (size_t)bq * 65536;
        dst = om + ((size_t)b * QP + (bq % QQ)) * PP;
        dsg = sg + ((size_t)b * QP + (bq % QQ)) * PP;
    }
    const uint4* tb = stb + (size_t)b * PP + (size_t)half * NBH;
    _Float16* dsth = dst + (size_t)half * NBH;
    _Float16* dsgh = dsg ? dsg + (size_t)half * NBH : nullptr;

    float l1 = 0.f, l2 = 0.f;

    // 3 batches of 8 points (stride 256), then a 128-thread tail point.
    #pragma unroll
    for (int bt = 0; bt < 3; ++bt) {
        int pb = bt * 2048 + tid;
        uint4 tt[8];
        #pragma unroll
        for (int i = 0; i < 8; ++i) tt[i] = tb[pb + i * 256];
        __builtin_amdgcn_sched_barrier(0);
        float g0[8], g1[8], g2[8], g3[8];
        #pragma unroll
        for (int i = 0; i < 8; ++i) {
            g0[i] = m[tt[i].x];
            g1[i] = m[tt[i].x + 1];
            g2[i] = m[tt[i].y];
            g3[i] = m[tt[i].y + 1];
        }
        __builtin_amdgcn_sched_barrier(0);
        #pragma unroll
        for (int i = 0; i < 8; ++i) {
            union { unsigned int u; _Float16 h[2]; } pw, pyw;
            pw.u = tt[i].z; pyw.u = tt[i].w;
            float wa = (float)pw.h[0], wb = (float)pw.h[1];
            float ya = (float)pyw.h[0], yb = (float)pyw.h[1];
            float v = ya * fmaf(wa, g0[i], wb * g1[i])
                    + yb * fmaf(wa, g2[i], wb * g3[i]);
            dsth[pb + i * 256] = (_Float16)v;
            if (is_t) {
                l1 += v;
            } else {
                float e = __expf(-fabsf(v));
                float q = 1.f / (1.f + e);
                float g = (v >= 0.f) ? q : e * q;
                dsgh[pb + i * 256] = (_Float16)g;
                l1 += fmaxf(v, 0.f) + __logf(1.f + e);
                l2 += g;
            }
        }
    }
    if (tid < 128) {
        int p = 6144 + tid;
        uint4 t = tb[p];
        float v00 = m[t.x], v01 = m[t.x + 1];
        float v10 = m[t.y], v11 = m[t.y + 1];
        union { unsigned int u; _Float16 h[2]; } pw, pyw;
        pw.u = t.z; pyw.u = t.w;
        float wa = (float)pw.h[0], wb = (float)pw.h[1];
        float ya = (float)pyw.h[0], yb = (float)pyw.h[1];
        float v = ya * fmaf(wa, v00, wb * v01) + yb * fmaf(wa, v10, wb * v11);
        dsth[p] = (_Float16)v;
        if (is_t) {
            l1 += v;
        } else {
            float e = __expf(-fabsf(v));
            float q = 1.f / (1.f + e);
            float g = (v >= 0.f) ? q : e * q;
            dsgh[p] = (_Float16)g;
            l1 += fmaxf(v, 0.f) + __logf(1.f + e);
            l2 += g;
        }
    }

    #pragma unroll
    for (int off = 32; off; off >>= 1) {
        l1 += __shfl_down(l1, off, 64);
        l2 += __shfl_down(l2, off, 64);
    }
    if ((tid & 63) == 0) { red[tid >> 6] = l1; red2[tid >> 6] = l2; }
    __syncthreads();
    if (tid == 0) {
        float t1 = red[0] + red[1] + red[2] + red[3];
        float t2 = red2[0] + red2[1] + red2[2] + red2[3];
        psum[(size_t)bid * 2] = t1;
        psum[(size_t)bid * 2 + 1] = t2;
    }
}

// grid (7 qt, 8 b, KS). 4 waves; wave w owns t-tile w. C1=om.tm^T, C2=sig.tm^T.
__global__ __launch_bounds__(256) void dot_mfma_kernel(
    const _Float16* __restrict__ om, const _Float16* __restrict__ sg,
    const _Float16* __restrict__ tm,
    float* __restrict__ part_om, float* __restrict__ part_s)
{
    int qt = blockIdx.x, b = blockIdx.y, ks = blockIdx.z;
    int tid = threadIdx.x, lane = tid & 63, w = tid >> 6;
    int ra = lane & 15;
    int ko = (lane >> 4) * 8;
    const _Float16* pa = om + ((size_t)(b * QP + qt * 16 + ra)) * PP + ks * KCH + ko;
    const _Float16* ps = sg + ((size_t)(b * QP + qt * 16 + ra)) * PP + ks * KCH + ko;
    const _Float16* pb = tm + ((size_t)(b * TP + w * 16 + ra)) * PP + ks * KCH + ko;
    f32x4 accO = {0.f, 0.f, 0.f, 0.f};
    f32x4 accS = {0.f, 0.f, 0.f, 0.f};
    #pragma unroll 7
    for (int k = 0; k < KCH / 32; ++k) {
        f16x8 a = *(const f16x8*)(pa + (size_t)k * 32);
        f16x8 s = *(const f16x8*)(ps + (size_t)k * 32);
        f16x8 bb = *(const f16x8*)(pb + (size_t)k * 32);
        accO = __builtin_amdgcn_mfma_f32_16x16x32_f16(a, bb, accO, 0, 0, 0);
        accS = __builtin_amdgcn_mfma_f32_16x16x32_f16(s, bb, accS, 0, 0, 0);
    }
    int t = w * 16 + ra;
    int q = qt * 16 + (lane >> 4) * 4;
    size_t bse = (((size_t)ks * BB + b) * QP + q) * TP + t;
    #pragma unroll
    for (int r = 0; r < 4; ++r) {
        part_om[bse + (size_t)r * TP] = accO[r];
        part_s[bse + (size_t)r * TP] = accS[r];
    }
}

__global__ __launch_bounds__(256) void epilogue_kernel(
    const float* __restrict__ part_om, const float* __restrict__ part_s,
    const float* __restrict__ psum, const float* __restrict__ pred_logits,
    const float* __restrict__ pred_obj, const int* __restrict__ labels,
    float* __restrict__ out)
{
    int i = blockIdx.x * 256 + threadIdx.x;
    if (i >= BB * QQ * TT) return;
    int t = i % TT;
    int bq = i / TT;
    int b = bq / QQ, q = bq % QQ;
    float dO = 0.f, dS = 0.f;
    #pragma unroll
    for (int ks = 0; ks < KS; ++ks) {
        size_t o = (((size_t)ks * BB + b) * QP + q) * TP + t;
        dO += part_om[o];
        dS += part_s[o];
    }
    int omid = NT + bq;
    int tmid = b * TT + t;
    float ns = 0.f, ss = 0.f, ts = 0.f;
    #pragma unroll
    for (int h = 0; h < SPLIT; ++h) {
        ns += psum[(size_t)(omid * SPLIT + h) * 2];
        ss += psum[(size_t)(omid * SPLIT + h) * 2 + 1];
        ts += psum[(size_t)(tmid * SPLIT + h) * 2];
    }
    float cmask = (ns - dO) * (1.f / PP);
    float cdice = 1.f - (2.f * dS + 1.f) / (ss + ts + 1.f);
    int label = labels[b * TT + t];
    float a0 = pred_obj[bq * 2], a1 = pred_obj[bq * 2 + 1];
    float prob;
    if (label == CC - 1) {
        prob = 1.f / (1.f + __expf(a0 - a1));
    } else {
        float pc = 1.f / (1.f + __expf(-pred_logits[(size_t)bq * CC + label]));
        float po = 1.f / (1.f + __expf(a1 - a0));
        prob = sqrtf(pc * po);
    }
    out[i] = 5.f * cmask - 2.f * prob + 5.f * cdice;
}

extern "C" void kernel_launch(void* const* d_in, const int* in_sizes, int n_in,
                              void* d_out, int out_size, void* d_ws, size_t ws_size,
                              hipStream_t stream) {
    const float* pred_logits = (const float*)d_in[0];
    const float* pred_obj    = (const float*)d_in[1];
    const float* pred_masks  = (const float*)d_in[2];
    const float* tgt_masks   = (const float*)d_in[3];
    const int*   tgt_labels  = (const int*)d_in[4];
    const float* coords      = (const float*)d_in[5];
    float* out = (float*)d_out;

    char* ws = (char*)d_ws;
    const size_t SZ_TB = (size_t)BB * PP * 16;           // 1,605,632
    const size_t SZ_OM = (size_t)BB * QP * PP * 2;       // 22,478,848
    const size_t SZ_TM = (size_t)BB * TP * PP * 2;       // 12,845,056
    const size_t SZ_PT = (size_t)KS * BB * QP * TP * 4;  // 1,835,008
    uint4* stb    = (uint4*)ws;
    _Float16* om  = (_Float16*)(ws + SZ_TB);
    _Float16* sg  = (_Float16*)(ws + SZ_TB + SZ_OM);
    _Float16* tmm = (_Float16*)(ws + SZ_TB + 2 * SZ_OM);
    float* part_om = (float*)(ws + SZ_TB + 2 * SZ_OM + SZ_TM);
    float* part_s  = (float*)(ws + SZ_TB + 2 * SZ_OM + SZ_TM + SZ_PT);
    float* psum    = (float*)(ws + SZ_TB + 2 * SZ_OM + SZ_TM + 2 * SZ_PT);

    hipLaunchKernelGGL(sort_kernel, dim3(BB), dim3(1024), 0, stream,
                       coords, stb);
    hipLaunchKernelGGL(sample_kernel, dim3(NMASK * SPLIT), dim3(256), 0, stream,
                       tgt_masks, pred_masks, stb, tmm, om, sg, psum);
    hipLaunchKernelGGL(dot_mfma_kernel, dim3(QP / 16, BB, KS), dim3(256), 0, stream,
                       om, sg, tmm, part_om, part_s);
    hipLaunchKernelGGL(epilogue_kernel, dim3((BB * QQ * TT + 255) / 256), dim3(256),
                       0, stream,
                       part_om, part_s, psum, pred_logits, pred_obj,
                       tgt_labels, out);
}

// Round 14
// 128.084 us; speedup vs baseline: 1.6237x; 1.6237x over previous
//
#include <hip/hip_runtime.h>
#include <math.h>

#define BB 8
#define QQ 100
#define CC 41
#define TT 50
#define PP 12544        // = 49 * 256
#define QP 112          // padded Q rows (7 * 16)
#define TP 64           // padded T rows (4 * 16)
#define KS 8            // split-K over P
#define KCH (PP / KS)   // 1568
#define NT (BB * TT)    // 400
#define NMASK (NT + BB * QQ)   // 1200
#define NCH 8           // 32-row chunks per mask
#define CROWS 33        // staged rows (32 + 1 halo)

typedef _Float16 f16x8 __attribute__((ext_vector_type(8)));
typedef float f32x4 __attribute__((ext_vector_type(4)));

#if defined(__has_builtin)
#if __has_builtin(__builtin_amdgcn_global_load_lds)
#define HAVE_GLL 1
#endif
#endif

// ---------------------------------------------------------------------------
// sort_kernel: one block per batch. LDS-atomic counting sort into 16 16-row
// bins (chunk = bin>>1). Within-bin order nondeterministic; consumers are
// permutation-invariant (fp jitter << threshold; validated in R12/R13).
// Entry: t.x/t.y = CHUNK-LOCAL float indices ((r&31)*256+xb); t.z/t.w = f16x2
// x-/y-weights with borders folded in.
// ---------------------------------------------------------------------------
__global__ __launch_bounds__(1024) void sort_kernel(
    const float* __restrict__ coords, uint4* __restrict__ stb,
    int* __restrict__ binStart)
{
    int b = blockIdx.x;
    int tid = threadIdx.x;
    const float2* cd = (const float2*)coords + (size_t)b * PP;
    __shared__ int hist[16];
    __shared__ int cur[16];
    if (tid < 16) hist[tid] = 0;
    __syncthreads();
    for (int p = tid; p < PP; p += 1024) {
        float y = fmaf(cd[p].y, 256.f, -0.5f);
        int bin = min(max((int)floorf(y), 0), 255) >> 4;
        atomicAdd(&hist[bin], 1);
    }
    __syncthreads();
    if (tid == 0) {
        int acc = 0;
        for (int i = 0; i < 16; ++i) {
            cur[i] = acc;
            binStart[b * 17 + i] = acc;
            acc += hist[i];
        }
        binStart[b * 17 + 16] = PP;
    }
    __syncthreads();
    uint4* out = stb + (size_t)b * PP;
    for (int p = tid; p < PP; p += 1024) {
        float2 cc = cd[p];
        float x = fmaf(cc.x, 256.f, -0.5f);
        float y = fmaf(cc.y, 256.f, -0.5f);
        float x0f = floorf(x), y0f = floorf(y);
        int x0 = (int)x0f, y0 = (int)y0f;
        int bin = min(max(y0, 0), 255) >> 4;
        float wx = x - x0f, wy = y - y0f;
        int xb = min(max(x0, 0), 254);
        int r0 = min(max(y0, 0), 255);
        int r1 = min(y0 + 1, 255);
        int base = (r0 >> 5) << 5;              // chunk base row
        float wa, wb;
        if (x0 < 0)        { wa = wx;       wb = 0.f; }
        else if (x0 > 254) { wa = 0.f;      wb = 1.f - wx; }
        else               { wa = 1.f - wx; wb = wx; }
        float ya = (y0 >= 0)  ? 1.f - wy : 0.f;
        float yb = (y0 < 255) ? wy       : 0.f;
        union { unsigned int u; _Float16 h[2]; } pw, pyw;
        pw.h[0] = (_Float16)wa;  pw.h[1] = (_Float16)wb;
        pyw.h[0] = (_Float16)ya; pyw.h[1] = (_Float16)yb;
        uint4 t;
        t.x = (unsigned int)((r0 - base) * 256 + xb);
        t.y = (unsigned int)((r1 - base) * 256 + xb);
        t.z = pw.u; t.w = pyw.u;
        int slot = atomicAdd(&cur[bin], 1);
        out[slot] = t;
    }
}

// ---------------------------------------------------------------------------
// sample_kernel: block (mask, chunk) of 512 thr, 9600 blocks, 4 blocks/CU.
// Stage 33 fp32 rows via global_load_lds DMA (no VGPR round-trip, ~4 instr/
// thread, whole chunk in flight), ONE vmcnt(0)+barrier, then sample this
// chunk's sorted points from LDS. Cross-block overlap hides the DMA.
// ---------------------------------------------------------------------------
__global__ __launch_bounds__(512, 8) void sample_kernel(
    const float* __restrict__ tgt_masks, const float* __restrict__ pred_masks,
    const uint4* __restrict__ stb, const int* __restrict__ binStart,
    _Float16* __restrict__ tm, _Float16* __restrict__ om, _Float16* __restrict__ sg,
    float* __restrict__ psum)
{
    __shared__ float buf[CROWS * 256];    // 33,792 B
    __shared__ float red[8], red2[8];
    int bid = blockIdx.x;
    int id = bid >> 3;
    int c = bid & 7;
    int tid = threadIdx.x;
    bool is_t = id < NT;
    int b;
    const float* m;
    _Float16* dst;
    _Float16* dsg = nullptr;
    if (is_t) {
        b = id / TT;
        m = tgt_masks + (size_t)id * 65536;
        dst = tm + ((size_t)b * TP + (id % TT)) * PP;
    } else {
        int bq = id - NT;
        b = bq / QQ;
        m = pred_masks + (size_t)bq * 65536;
        dst = om + ((size_t)b * QP + (bq % QQ)) * PP;
        dsg = sg + ((size_t)b * QP + (bq % QQ)) * PP;
    }

    // ---- DMA-stage rows [32c, 32c+33) (32 for the last chunk) ----
    {
        int nv4 = ((c == NCH - 1) ? 32 : CROWS) * 64;   // uint4 count
        const float* gsrc = m + c * 32 * 256;
        #pragma unroll
        for (int j = 0; j < 5; ++j) {
            int idx = j * 512 + tid;
            if (idx < nv4) {
#ifdef HAVE_GLL
                __builtin_amdgcn_global_load_lds(
                    (const __attribute__((address_space(1))) unsigned int*)(gsrc + idx * 4),
                    (__attribute__((address_space(3))) unsigned int*)(buf + idx * 4),
                    16, 0, 0);
#else
                *(uint4*)(buf + idx * 4) = *(const uint4*)(gsrc + idx * 4);
#endif
            }
        }
    }
    asm volatile("s_waitcnt vmcnt(0)" ::: "memory");
    __syncthreads();

    const uint4* tb = stb + (size_t)b * PP;
    const int* bs = binStart + b * 17;
    int ps = bs[2 * c], pe = bs[2 * c + 2];

    float l1 = 0.f, l2 = 0.f;
    for (int p = ps + tid; p < pe; p += 512) {
        uint4 t = tb[p];
        float v00 = buf[t.x], v01 = buf[t.x + 1];
        float v10 = buf[t.y], v11 = buf[t.y + 1];
        union { unsigned int u; _Float16 h[2]; } pw, pyw;
        pw.u = t.z; pyw.u = t.w;
        float wa = (float)pw.h[0], wb = (float)pw.h[1];
        float ya = (float)pyw.h[0], yb = (float)pyw.h[1];
        float v = ya * fmaf(wa, v00, wb * v01) + yb * fmaf(wa, v10, wb * v11);
        dst[p] = (_Float16)v;
        if (is_t) {
            l1 += v;
        } else {
            float e = __expf(-fabsf(v));
            float q = 1.f / (1.f + e);
            float g = (v >= 0.f) ? q : e * q;
            dsg[p] = (_Float16)g;
            l1 += fmaxf(v, 0.f) + __logf(1.f + e);
            l2 += g;
        }
    }

    #pragma unroll
    for (int off = 32; off; off >>= 1) {
        l1 += __shfl_down(l1, off, 64);
        l2 += __shfl_down(l2, off, 64);
    }
    if ((tid & 63) == 0) { red[tid >> 6] = l1; red2[tid >> 6] = l2; }
    __syncthreads();
    if (tid == 0) {
        float t1 = 0.f, t2 = 0.f;
        #pragma unroll
        for (int w = 0; w < 8; ++w) { t1 += red[w]; t2 += red2[w]; }
        psum[(size_t)bid * 2] = t1;
        psum[(size_t)bid * 2 + 1] = t2;
    }
}

// grid (7 qt, 8 b, KS). 4 waves; wave w owns t-tile w. C1=om.tm^T, C2=sig.tm^T.
__global__ __launch_bounds__(256) void dot_mfma_kernel(
    const _Float16* __restrict__ om, const _Float16* __restrict__ sg,
    const _Float16* __restrict__ tm,
    float* __restrict__ part_om, float* __restrict__ part_s)
{
    int qt = blockIdx.x, b = blockIdx.y, ks = blockIdx.z;
    int tid = threadIdx.x, lane = tid & 63, w = tid >> 6;
    int ra = lane & 15;
    int ko = (lane >> 4) * 8;
    const _Float16* pa = om + ((size_t)(b * QP + qt * 16 + ra)) * PP + ks * KCH + ko;
    const _Float16* ps = sg + ((size_t)(b * QP + qt * 16 + ra)) * PP + ks * KCH + ko;
    const _Float16* pb = tm + ((size_t)(b * TP + w * 16 + ra)) * PP + ks * KCH + ko;
    f32x4 accO = {0.f, 0.f, 0.f, 0.f};
    f32x4 accS = {0.f, 0.f, 0.f, 0.f};
    #pragma unroll 7
    for (int k = 0; k < KCH / 32; ++k) {
        f16x8 a = *(const f16x8*)(pa + (size_t)k * 32);
        f16x8 s = *(const f16x8*)(ps + (size_t)k * 32);
        f16x8 bb = *(const f16x8*)(pb + (size_t)k * 32);
        accO = __builtin_amdgcn_mfma_f32_16x16x32_f16(a, bb, accO, 0, 0, 0);
        accS = __builtin_amdgcn_mfma_f32_16x16x32_f16(s, bb, accS, 0, 0, 0);
    }
    int t = w * 16 + ra;
    int q = qt * 16 + (lane >> 4) * 4;
    size_t bse = (((size_t)ks * BB + b) * QP + q) * TP + t;
    #pragma unroll
    for (int r = 0; r < 4; ++r) {
        part_om[bse + (size_t)r * TP] = accO[r];
        part_s[bse + (size_t)r * TP] = accS[r];
    }
}

__global__ __launch_bounds__(256) void epilogue_kernel(
    const float* __restrict__ part_om, const float* __restrict__ part_s,
    const float* __restrict__ psum, const float* __restrict__ pred_logits,
    const float* __restrict__ pred_obj, const int* __restrict__ labels,
    float* __restrict__ out)
{
    int i = blockIdx.x * 256 + threadIdx.x;
    if (i >= BB * QQ * TT) return;
    int t = i % TT;
    int bq = i / TT;
    int b = bq / QQ, q = bq % QQ;
    float dO = 0.f, dS = 0.f;
    #pragma unroll
    for (int ks = 0; ks < KS; ++ks) {
        size_t o = (((size_t)ks * BB + b) * QP + q) * TP + t;
        dO += part_om[o];
        dS += part_s[o];
    }
    int omid = NT + bq;
    int tmid = b * TT + t;
    float ns = 0.f, ss = 0.f, ts = 0.f;
    #pragma unroll
    for (int j = 0; j < NCH; ++j) {
        ns += psum[(size_t)(omid * NCH + j) * 2];
        ss += psum[(size_t)(omid * NCH + j) * 2 + 1];
        ts += psum[(size_t)(tmid * NCH + j) * 2];
    }
    float cmask = (ns - dO) * (1.f / PP);
    float cdice = 1.f - (2.f * dS + 1.f) / (ss + ts + 1.f);
    int label = labels[b * TT + t];
    float a0 = pred_obj[bq * 2], a1 = pred_obj[bq * 2 + 1];
    float prob;
    if (label == CC - 1) {
        prob = 1.f / (1.f + __expf(a0 - a1));
    } else {
        float pc = 1.f / (1.f + __expf(-pred_logits[(size_t)bq * CC + label]));
        float po = 1.f / (1.f + __expf(a1 - a0));
        prob = sqrtf(pc * po);
    }
    out[i] = 5.f * cmask - 2.f * prob + 5.f * cdice;
}

extern "C" void kernel_launch(void* const* d_in, const int* in_sizes, int n_in,
                              void* d_out, int out_size, void* d_ws, size_t ws_size,
                              hipStream_t stream) {
    const float* pred_logits = (const float*)d_in[0];
    const float* pred_obj    = (const float*)d_in[1];
    const float* pred_masks  = (const float*)d_in[2];
    const float* tgt_masks   = (const float*)d_in[3];
    const int*   tgt_labels  = (const int*)d_in[4];
    const float* coords      = (const float*)d_in[5];
    float* out = (float*)d_out;

    char* ws = (char*)d_ws;
    const size_t SZ_TB = (size_t)BB * PP * 16;           // 1,605,632
    const size_t SZ_BS = 1024;
    const size_t SZ_OM = (size_t)BB * QP * PP * 2;       // 22,478,848
    const size_t SZ_TM = (size_t)BB * TP * PP * 2;       // 12,845,056
    const size_t SZ_PT = (size_t)KS * BB * QP * TP * 4;  // 1,835,008
    uint4* stb    = (uint4*)ws;
    int* binStart = (int*)(ws + SZ_TB);
    _Float16* om  = (_Float16*)(ws + SZ_TB + SZ_BS);
    _Float16* sg  = (_Float16*)(ws + SZ_TB + SZ_BS + SZ_OM);
    _Float16* tmm = (_Float16*)(ws + SZ_TB + SZ_BS + 2 * SZ_OM);
    float* part_om = (float*)(ws + SZ_TB + SZ_BS + 2 * SZ_OM + SZ_TM);
    float* part_s  = (float*)(ws + SZ_TB + SZ_BS + 2 * SZ_OM + SZ_TM + SZ_PT);
    float* psum    = (float*)(ws + SZ_TB + SZ_BS + 2 * SZ_OM + SZ_TM + 2 * SZ_PT);

    hipLaunchKernelGGL(sort_kernel, dim3(BB), dim3(1024), 0, stream,
                       coords, stb, binStart);
    hipLaunchKernelGGL(sample_kernel, dim3(NMASK * NCH), dim3(512), 0, stream,
                       tgt_masks, pred_masks, stb, binStart, tmm, om, sg, psum);
    hipLaunchKernelGGL(dot_mfma_kernel, dim3(QP / 16, BB, KS), dim3(256), 0, stream,
                       om, sg, tmm, part_om, part_s);
    hipLaunchKernelGGL(epilogue_kernel, dim3((BB * QQ * TT + 255) / 256), dim3(256),
                       0, stream,
                       part_om, part_s, psum, pred_logits, pred_obj,
                       tgt_labels, out);
}